// Round 5
// baseline (1197.181 us; speedup 1.0000x reference)
//
#include <hip/hip_runtime.h>
#include <hip/hip_bf16.h>
#include <stdint.h>

#define TT   8192   // B*S tokens
#define DD   2048
#define MM   2048
#define NE   8

typedef float f32x4 __attribute__((ext_vector_type(4)));
typedef short s16x8 __attribute__((ext_vector_type(8)));
typedef unsigned int u32;

static __device__ __forceinline__ short f2bf(float f) {
  __hip_bfloat16 h = __float2bfloat16(f);
  short s;
  __builtin_memcpy(&s, &h, 2);
  return s;
}

static __device__ __forceinline__ void gload_lds16(const short* g, short* lds) {
  __builtin_amdgcn_global_load_lds(
      (const __attribute__((address_space(1))) u32*)g,
      (__attribute__((address_space(3))) u32*)lds, 16, 0, 0);
}

#define VMCNT(n) asm volatile("s_waitcnt vmcnt(" #n ")" ::: "memory")
#define BAR()    __builtin_amdgcn_s_barrier()
#define SCHEDB() __builtin_amdgcn_sched_barrier(0)

// ---------------- fp32 -> bf16 conversion (x) ----------------
__global__ __launch_bounds__(256) void cvt_kernel(const float* __restrict__ in,
                                                  short* __restrict__ out, size_t n) {
  size_t idx = ((size_t)blockIdx.x * 256 + threadIdx.x) * 8;
  size_t stride = (size_t)gridDim.x * 256 * 8;
  for (size_t i = idx; i < n; i += stride) {
    f32x4 a = *(const f32x4*)(in + i);
    f32x4 b = *(const f32x4*)(in + i + 4);
    s16x8 v;
    v[0]=f2bf(a[0]); v[1]=f2bf(a[1]); v[2]=f2bf(a[2]); v[3]=f2bf(a[3]);
    v[4]=f2bf(b[0]); v[5]=f2bf(b[1]); v[6]=f2bf(b[2]); v[7]=f2bf(b[3]);
    *(s16x8*)(out + i) = v;
  }
}

// ---------------- fp32 -> bf16 transposing conversion (weights) ----------------
__global__ __launch_bounds__(256) void tcvt_kernel(
    const float* __restrict__ w0, const float* __restrict__ w1, const float* __restrict__ w2,
    short* __restrict__ o0, short* __restrict__ o1, short* __restrict__ o2) {
  __shared__ short tile[64][65];
  const int bz = blockIdx.z;                 // 0..23: weight = bz>>3, expert = bz&7
  const float* in; short* out;
  if (bz < 8)       { in = w0; out = o0; }
  else if (bz < 16) { in = w1; out = o1; }
  else              { in = w2; out = o2; }
  const int ex = bz & 7;
  const float* src = in + (size_t)ex * DD * MM;
  short* dst = out + (size_t)ex * DD * MM;
  const int r0 = blockIdx.y * 64;            // source row (k)
  const int c0 = blockIdx.x * 64;            // source col (n)
  const int t = threadIdx.x;
  const int rr = t >> 4, cc = (t & 15) * 4;
  #pragma unroll
  for (int i = 0; i < 4; i++) {
    int row = rr + i * 16;
    f32x4 v = *(const f32x4*)(src + (size_t)(r0 + row) * MM + c0 + cc);
    tile[cc + 0][row] = f2bf(v[0]);
    tile[cc + 1][row] = f2bf(v[1]);
    tile[cc + 2][row] = f2bf(v[2]);
    tile[cc + 3][row] = f2bf(v[3]);
  }
  __syncthreads();
  const int orow = t >> 2, c8 = (t & 3) * 16;
  s16x8 v0, v1;
  #pragma unroll
  for (int i = 0; i < 8; i++) { v0[i] = tile[orow][c8 + i]; v1[i] = tile[orow][c8 + 8 + i]; }
  short* dp = dst + (size_t)(c0 + orow) * DD + r0 + c8;
  *(s16x8*)(dp) = v0;
  *(s16x8*)(dp + 8) = v1;
}

// ---------------- gate: fp32 logits, top-2, softmax ----------------
__global__ __launch_bounds__(256) void gate_kernel(const float* __restrict__ x,
    const float* __restrict__ gk, int* __restrict__ counts,
    int* __restrict__ tkidx, float* __restrict__ tkw) {
  int t = blockIdx.x;
  const float* xr = x + (size_t)t * DD;
  float acc[NE];
  #pragma unroll
  for (int e = 0; e < NE; e++) acc[e] = 0.f;
  for (int d = threadIdx.x; d < DD; d += 256) {
    float xv = xr[d];
    const float* g = gk + (size_t)d * NE;
    #pragma unroll
    for (int e = 0; e < NE; e++) acc[e] += xv * g[e];
  }
  #pragma unroll
  for (int e = 0; e < NE; e++) {
    #pragma unroll
    for (int off = 32; off >= 1; off >>= 1)
      acc[e] += __shfl_xor(acc[e], off, 64);
  }
  __shared__ float red[4][NE];
  int wid = threadIdx.x >> 6;
  int lane = threadIdx.x & 63;
  if (lane == 0) {
    #pragma unroll
    for (int e = 0; e < NE; e++) red[wid][e] = acc[e];
  }
  __syncthreads();
  if (threadIdx.x == 0) {
    float l[NE];
    #pragma unroll
    for (int e = 0; e < NE; e++) l[e] = red[0][e] + red[1][e] + red[2][e] + red[3][e];
    int i1 = 0; float v1 = l[0];
    #pragma unroll
    for (int e = 1; e < NE; e++) if (l[e] > v1) { v1 = l[e]; i1 = e; }
    int i2 = -1; float v2 = -1e30f;
    #pragma unroll
    for (int e = 0; e < NE; e++) if (e != i1 && l[e] > v2) { v2 = l[e]; i2 = e; }
    float p = __expf(v2 - v1);           // v1 >= v2
    float inv = 1.f / (1.f + p);
    tkidx[t*2]   = i1; tkidx[t*2+1] = i2;
    tkw[t*2]     = inv; tkw[t*2+1]  = p * inv;
    atomicAdd(&counts[i1], 1);
    atomicAdd(&counts[i2], 1);
  }
}

// ---------------- scatter into per-expert compact lists ----------------
__global__ __launch_bounds__(256) void scatter_kernel(const int* __restrict__ counts,
    int* __restrict__ offsets, const int* __restrict__ tkidx,
    const float* __restrict__ tkw, int* __restrict__ ltok, float* __restrict__ lwt) {
  __shared__ int soff[NE];
  __shared__ int scur[NE];
  if (threadIdx.x == 0) {
    int s = 0;
    for (int e = 0; e < NE; e++) { offsets[e] = s; soff[e] = s; s += counts[e]; scur[e] = 0; }
    offsets[NE] = s;
  }
  __syncthreads();
  for (int i = threadIdx.x; i < TT * 2; i += 256) {
    int e = tkidx[i];
    int pos = atomicAdd(&scur[e], 1);
    int dst = soff[e] + pos;
    ltok[dst] = i >> 1;
    lwt[dst]  = tkw[i];
  }
}

// ---------------- segment lookup ----------------
__device__ __forceinline__ void find_seg(const int* __restrict__ offsets, int tile, int bm,
                                         int& e, int& row0, int& rows, int& seg) {
  e = -1; row0 = 0; rows = 0; seg = 0;
  int accT = 0, prev = offsets[0];
  #pragma unroll
  for (int i = 0; i < NE; i++) {
    int nxt = offsets[i+1];
    int cnt = nxt - prev;
    int nt = (cnt + bm - 1) / bm;
    if (e < 0 && tile < accT + nt) { e = i; row0 = (tile - accT) * bm; rows = cnt; seg = prev; }
    accT += nt; prev = nxt;
  }
}

// ================= GEMM1: uniform-order counted-vmcnt pipeline =================
// BM=256, dual-B 128 cols, BK=64, 512 thr = 8 waves (2Mx4N). Per wave 128x32 per mat.
// Per-wave per-tile issue order (UNIFORM across waves): [B0 x2, A x4, B1 x2].
// Waits: q0 vmcnt(2) (B0+A done), q1 vmcnt(2) (B1 done). Never 0 except tail.
#define MAXT1 72

__global__ __launch_bounds__(512, 2) void gemm1_fast(
    const short* __restrict__ xbf,
    const short* __restrict__ w0t, const short* __restrict__ w1t,
    const int* __restrict__ offsets,
    const int* __restrict__ ltok, const float* __restrict__ lwt,
    short* __restrict__ hbuf) {
  __shared__ short As[2][256 * 64];
  __shared__ short B0s[2][128 * 64];
  __shared__ short B1s[2][128 * 64];
  __shared__ float w_s[256];

  const int tile = blockIdx.x;
  const int n0 = blockIdx.y * 128;
  int e, row0, rows, seg;
  find_seg(offsets, tile, 256, e, row0, rows, seg);
  if (e < 0) return;

  const int tid = threadIdx.x;
  const int lane = tid & 63, wid = tid >> 6;
  if (tid < 256) {
    int gr = row0 + tid;
    w_s[tid] = (gr < rows) ? lwt[seg + gr] : 0.f;
  }

  // staging geometry: chunk = 8 rows; lane l covers row chunkbase+(l>>3), 16B seg (l&7)
  const int swz = ((lane & 7) ^ (lane >> 3)) * 8;   // pre-swizzled source offset (shorts)
  // A: wave wid owns chunks 4w..4w+3 (rows 32w..32w+31)
  const short* aSrc[4];
  #pragma unroll
  for (int c = 0; c < 4; c++) {
    int gr = row0 + 32 * wid + 8 * c + (lane >> 3);
    if (gr >= rows) gr = rows - 1;
    aSrc[c] = xbf + (size_t)ltok[seg + gr] * DD + swz;
  }
  const int aDst = (32 * wid) * 64;                 // + c*512
  // B0/B1: wave wid owns chunks 2w,2w+1 (rows 16w..16w+15)
  const short* b0Src[2]; const short* b1Src[2];
  #pragma unroll
  for (int j = 0; j < 2; j++) {
    int n = n0 + 16 * wid + 8 * j + (lane >> 3);
    b0Src[j] = w0t + ((size_t)e * MM + n) * DD + swz;
    b1Src[j] = w1t + ((size_t)e * MM + n) * DD + swz;
  }
  const int bDst = (16 * wid) * 64;                 // + j*512

  const int wr = wid >> 2, wn = wid & 3;
  const int lr = lane & 15;
  const int kq = (lane >> 4) * 8;
  const int lq = lane >> 4;

  f32x4 acc0[8][2], acc1[8][2];
  #pragma unroll
  for (int i = 0; i < 8; i++)
    #pragma unroll
    for (int j = 0; j < 2; j++) { acc0[i][j] = 0.f; acc1[i][j] = 0.f; }

  int arow_[8], akey_[8];
  #pragma unroll
  for (int mi = 0; mi < 8; mi++) {
    arow_[mi] = wr * 128 + mi * 16 + lr;
    akey_[mi] = (arow_[mi] & 7) * 8;
  }
  int brow_[2], bkey_[2];
  #pragma unroll
  for (int ni = 0; ni < 2; ni++) {
    brow_[ni] = wn * 32 + ni * 16 + lr;
    bkey_[ni] = (brow_[ni] & 7) * 8;
  }

  __syncthreads();   // w_s visible

  // prologue: tile 0 into buf 0, order [B0,B0, A,A,A,A, B1,B1]
  gload_lds16(b0Src[0], &B0s[0][bDst]);
  gload_lds16(b0Src[1], &B0s[0][bDst + 512]);
  #pragma unroll
  for (int c = 0; c < 4; c++) gload_lds16(aSrc[c], &As[0][aDst + c * 512]);
  gload_lds16(b1Src[0], &B1s[0][bDst]);
  gload_lds16(b1Src[1], &B1s[0][bDst + 512]);

  const int NT = DD / 64;
  int b = 0;
  for (int t = 0; t < NT; ++t, b ^= 1) {
    const int nb = b ^ 1;
    const bool pf = (t + 1 < NT);
    const int kn = (t + 1) * 64;
    s16x8 a[8], bf0[2], bf1[2];

    // ---- q0: ks0, mat0.  needs: all A + all B0 of tile t ----
    VMCNT(2);
    BAR(); SCHEDB();
    if (pf) { gload_lds16(b0Src[0] + kn, &B0s[nb][bDst]); gload_lds16(b0Src[1] + kn, &B0s[nb][bDst + 512]); }
    #pragma unroll
    for (int mi = 0; mi < 8; mi++)
      a[mi] = *(const s16x8*)&As[b][arow_[mi] * 64 + (kq ^ akey_[mi])];
    #pragma unroll
    for (int ni = 0; ni < 2; ni++)
      bf0[ni] = *(const s16x8*)&B0s[b][brow_[ni] * 64 + (kq ^ bkey_[ni])];
    __builtin_amdgcn_s_setprio(1);
    #pragma unroll
    for (int mi = 0; mi < 8; mi++)
      #pragma unroll
      for (int ni = 0; ni < 2; ni++)
        acc0[mi][ni] = __builtin_amdgcn_mfma_f32_16x16x32_bf16(a[mi], bf0[ni], acc0[mi][ni], 0, 0, 0);
    __builtin_amdgcn_s_setprio(0);

    // ---- q1: ks0, mat1.  needs: all B1 of tile t ----
    if (pf) { VMCNT(2); } else { VMCNT(0); }
    BAR(); SCHEDB();
    if (pf) { gload_lds16(aSrc[0] + kn, &As[nb][aDst]); gload_lds16(aSrc[1] + kn, &As[nb][aDst + 512]); }
    #pragma unroll
    for (int ni = 0; ni < 2; ni++)
      bf1[ni] = *(const s16x8*)&B1s[b][brow_[ni] * 64 + (kq ^ bkey_[ni])];
    __builtin_amdgcn_s_setprio(1);
    #pragma unroll
    for (int mi = 0; mi < 8; mi++)
      #pragma unroll
      for (int ni = 0; ni < 2; ni++)
        acc1[mi][ni] = __builtin_amdgcn_mfma_f32_16x16x32_bf16(a[mi], bf1[ni], acc1[mi][ni], 0, 0, 0);
    __builtin_amdgcn_s_setprio(0);

    // ---- q2: ks1, mat0 (data already resident) ----
    BAR(); SCHEDB();
    if (pf) { gload_lds16(aSrc[2] + kn, &As[nb][aDst + 1024]); gload_lds16(aSrc[3] + kn, &As[nb][aDst + 1536]); }
    #pragma unroll
    for (int mi = 0; mi < 8; mi++)
      a[mi] = *(const s16x8*)&As[b][arow_[mi] * 64 + ((32 + kq) ^ akey_[mi])];
    #pragma unroll
    for (int ni = 0; ni < 2; ni++)
      bf0[ni] = *(const s16x8*)&B0s[b][brow_[ni] * 64 + ((32 + kq) ^ bkey_[ni])];
    __builtin_amdgcn_s_setprio(1);
    #pragma unroll
    for (int mi = 0; mi < 8; mi++)
      #pragma unroll
      for (int ni = 0; ni < 2; ni++)
        acc0[mi][ni] = __builtin_amdgcn_mfma_f32_16x16x32_bf16(a[mi], bf0[ni], acc0[mi][ni], 0, 0, 0);
    __builtin_amdgcn_s_setprio(0);

    // ---- q3: ks1, mat1 ----
    BAR(); SCHEDB();
    if (pf) { gload_lds16(b1Src[0] + kn, &B1s[nb][bDst]); gload_lds16(b1Src[1] + kn, &B1s[nb][bDst + 512]); }
    #pragma unroll
    for (int ni = 0; ni < 2; ni++)
      bf1[ni] = *(const s16x8*)&B1s[b][brow_[ni] * 64 + ((32 + kq) ^ bkey_[ni])];
    __builtin_amdgcn_s_setprio(1);
    #pragma unroll
    for (int mi = 0; mi < 8; mi++)
      #pragma unroll
      for (int ni = 0; ni < 2; ni++)
        acc1[mi][ni] = __builtin_amdgcn_mfma_f32_16x16x32_bf16(a[mi], bf1[ni], acc1[mi][ni], 0, 0, 0);
    __builtin_amdgcn_s_setprio(0);
  }

  // ---- epilogue: silu(h0)*h1*w -> bf16 hbuf ----
  #pragma unroll
  for (int mi = 0; mi < 8; mi++) {
    #pragma unroll
    for (int jj = 0; jj < 4; jj++) {
      int r = wr * 128 + mi * 16 + lq * 4 + jj;
      int gr = row0 + r;
      if (gr < rows) {
        float wgt = w_s[r];
        size_t hrow = (size_t)(seg + gr) * MM + n0;
        #pragma unroll
        for (int ni = 0; ni < 2; ni++) {
          int c = wn * 32 + ni * 16 + lr;
          float g = acc0[mi][ni][jj];
          float u = acc1[mi][ni][jj];
          float act = g / (1.f + __expf(-g));
          hbuf[hrow + c] = f2bf(act * u * wgt);
        }
      }
    }
  }
}

// ================= GEMM2: uniform-order counted-vmcnt pipeline =================
// BM=256, BN=256, BK=64. 512 thr = 8 waves (2Mx4N), per wave 128x64.
// B rows split into even/odd 32-row groups: q0 uses even groups, q1 odd.
// Per-wave issue order: [B_even x2, A x4, B_odd x2]. q0 vmcnt(2); q1 vmcnt(2).
#define MAXT2 72

__global__ __launch_bounds__(512, 2) void gemm2_fast(
    const short* __restrict__ hbuf,
    const short* __restrict__ wot,
    const int* __restrict__ offsets,
    const int* __restrict__ ltok,
    float* __restrict__ out) {
  __shared__ short As[2][256 * 64];
  __shared__ short Bs[2][256 * 64];
  __shared__ int tok_s[256];

  const int tile = blockIdx.x;
  const int n0 = blockIdx.y * 256;
  int e, row0, rows, seg;
  find_seg(offsets, tile, 256, e, row0, rows, seg);
  if (e < 0) return;

  const int tid = threadIdx.x;
  const int lane = tid & 63, wid = tid >> 6;
  if (tid < 256) {
    int gr = row0 + tid;
    tok_s[tid] = (gr < rows) ? ltok[seg + gr] : -1;
  }

  const int swz = ((lane & 7) ^ (lane >> 3)) * 8;
  // A: wave wid owns chunks 4w..4w+3 (rows 32w..32w+31)
  const short* aSrc[4];
  #pragma unroll
  for (int c = 0; c < 4; c++) {
    int gr = row0 + 32 * wid + 8 * c + (lane >> 3);
    if (gr >= rows) gr = rows - 1;
    aSrc[c] = hbuf + (size_t)(seg + gr) * MM + swz;
  }
  const int aDst = (32 * wid) * 64;
  // B even-group chunks: c0 = (w>>1)*8 + (w&1)*2 (+1); odd-group: +4
  const int c0 = (wid >> 1) * 8 + (wid & 1) * 2;
  const short* bSrcE[2]; const short* bSrcO[2];
  #pragma unroll
  for (int j = 0; j < 2; j++) {
    int nE = n0 + (c0 + j) * 8 + (lane >> 3);
    int nO = n0 + (c0 + 4 + j) * 8 + (lane >> 3);
    bSrcE[j] = wot + ((size_t)e * DD + nE) * MM + swz;
    bSrcO[j] = wot + ((size_t)e * DD + nO) * MM + swz;
  }
  const int bDstE = c0 * 512;
  const int bDstO = (c0 + 4) * 512;

  const int wr = wid >> 2, wn = wid & 3;
  const int lr = lane & 15;
  const int kq = (lane >> 4) * 8;
  const int lq = lane >> 4;

  f32x4 acc[8][4];
  #pragma unroll
  for (int i = 0; i < 8; i++)
    #pragma unroll
    for (int j = 0; j < 4; j++) acc[i][j] = 0.f;

  int arow_[8], akey_[8];
  #pragma unroll
  for (int mi = 0; mi < 8; mi++) {
    arow_[mi] = wr * 128 + mi * 16 + lr;
    akey_[mi] = (arow_[mi] & 7) * 8;
  }
  int brow_[4], bkey_[4];
  #pragma unroll
  for (int ni = 0; ni < 4; ni++) {
    brow_[ni] = wn * 64 + ni * 16 + lr;
    bkey_[ni] = (brow_[ni] & 7) * 8;
  }

  __syncthreads();

  // prologue: [B_even x2, A x4, B_odd x2] into buf 0
  gload_lds16(bSrcE[0], &Bs[0][bDstE]);
  gload_lds16(bSrcE[1], &Bs[0][bDstE + 512]);
  #pragma unroll
  for (int c = 0; c < 4; c++) gload_lds16(aSrc[c], &As[0][aDst + c * 512]);
  gload_lds16(bSrcO[0], &Bs[0][bDstO]);
  gload_lds16(bSrcO[1], &Bs[0][bDstO + 512]);

  const int NT = MM / 64;
  int b = 0;
  for (int t = 0; t < NT; ++t, b ^= 1) {
    const int nb = b ^ 1;
    const bool pf = (t + 1 < NT);
    const int kn = (t + 1) * 64;
    s16x8 a[8], bf_[4];

    // ---- q0: ks0, ni 0-1 (B even groups) ----
    VMCNT(2);
    BAR(); SCHEDB();
    if (pf) { gload_lds16(bSrcE[0] + kn, &Bs[nb][bDstE]); gload_lds16(bSrcE[1] + kn, &Bs[nb][bDstE + 512]); }
    #pragma unroll
    for (int mi = 0; mi < 8; mi++)
      a[mi] = *(const s16x8*)&As[b][arow_[mi] * 64 + (kq ^ akey_[mi])];
    #pragma unroll
    for (int ni = 0; ni < 2; ni++)
      bf_[ni] = *(const s16x8*)&Bs[b][brow_[ni] * 64 + (kq ^ bkey_[ni])];
    __builtin_amdgcn_s_setprio(1);
    #pragma unroll
    for (int mi = 0; mi < 8; mi++)
      #pragma unroll
      for (int ni = 0; ni < 2; ni++)
        acc[mi][ni] = __builtin_amdgcn_mfma_f32_16x16x32_bf16(a[mi], bf_[ni], acc[mi][ni], 0, 0, 0);
    __builtin_amdgcn_s_setprio(0);

    // ---- q1: ks0, ni 2-3 (B odd groups) ----
    if (pf) { VMCNT(2); } else { VMCNT(0); }
    BAR(); SCHEDB();
    if (pf) { gload_lds16(aSrc[0] + kn, &As[nb][aDst]); gload_lds16(aSrc[1] + kn, &As[nb][aDst + 512]); }
    #pragma unroll
    for (int ni = 2; ni < 4; ni++)
      bf_[ni] = *(const s16x8*)&Bs[b][brow_[ni] * 64 + (kq ^ bkey_[ni])];
    __builtin_amdgcn_s_setprio(1);
    #pragma unroll
    for (int mi = 0; mi < 8; mi++)
      #pragma unroll
      for (int ni = 2; ni < 4; ni++)
        acc[mi][ni] = __builtin_amdgcn_mfma_f32_16x16x32_bf16(a[mi], bf_[ni], acc[mi][ni], 0, 0, 0);
    __builtin_amdgcn_s_setprio(0);

    // ---- q2: ks1, ni 0-1 ----
    BAR(); SCHEDB();
    if (pf) { gload_lds16(aSrc[2] + kn, &As[nb][aDst + 1024]); gload_lds16(aSrc[3] + kn, &As[nb][aDst + 1536]); }
    #pragma unroll
    for (int mi = 0; mi < 8; mi++)
      a[mi] = *(const s16x8*)&As[b][arow_[mi] * 64 + ((32 + kq) ^ akey_[mi])];
    #pragma unroll
    for (int ni = 0; ni < 2; ni++)
      bf_[ni] = *(const s16x8*)&Bs[b][brow_[ni] * 64 + ((32 + kq) ^ bkey_[ni])];
    __builtin_amdgcn_s_setprio(1);
    #pragma unroll
    for (int mi = 0; mi < 8; mi++)
      #pragma unroll
      for (int ni = 0; ni < 2; ni++)
        acc[mi][ni] = __builtin_amdgcn_mfma_f32_16x16x32_bf16(a[mi], bf_[ni], acc[mi][ni], 0, 0, 0);
    __builtin_amdgcn_s_setprio(0);

    // ---- q3: ks1, ni 2-3 ----
    BAR(); SCHEDB();
    if (pf) { gload_lds16(bSrcO[0] + kn, &Bs[nb][bDstO]); gload_lds16(bSrcO[1] + kn, &Bs[nb][bDstO + 512]); }
    #pragma unroll
    for (int ni = 2; ni < 4; ni++)
      bf_[ni] = *(const s16x8*)&Bs[b][brow_[ni] * 64 + ((32 + kq) ^ bkey_[ni])];
    __builtin_amdgcn_s_setprio(1);
    #pragma unroll
    for (int mi = 0; mi < 8; mi++)
      #pragma unroll
      for (int ni = 2; ni < 4; ni++)
        acc[mi][ni] = __builtin_amdgcn_mfma_f32_16x16x32_bf16(a[mi], bf_[ni], acc[mi][ni], 0, 0, 0);
    __builtin_amdgcn_s_setprio(0);
  }

  #pragma unroll
  for (int mi = 0; mi < 8; mi++) {
    #pragma unroll
    for (int jj = 0; jj < 4; jj++) {
      int r = wr * 128 + mi * 16 + lq * 4 + jj;
      int gr = row0 + r;
      if (gr < rows) {
        size_t orow = (size_t)tok_s[r] * DD + n0;
        #pragma unroll
        for (int ni = 0; ni < 4; ni++) {
          int c = wn * 64 + ni * 16 + lr;
          atomicAdd(&out[orow + c], acc[mi][ni][jj]);
        }
      }
    }
  }
}

// ---------------- launcher ----------------
extern "C" void kernel_launch(void* const* d_in, const int* in_sizes, int n_in,
                              void* d_out, int out_size, void* d_ws, size_t ws_size,
                              hipStream_t stream) {
  const float* x   = (const float*)d_in[0];
  const float* gk  = (const float*)d_in[1];
  const float* wi0 = (const float*)d_in[2];
  const float* wi1 = (const float*)d_in[3];
  const float* wo  = (const float*)d_in[4];
  float* out = (float*)d_out;

  char* w = (char*)d_ws;
  int*   counts  = (int*)(w);
  int*   offsets = (int*)(w + 256);
  int*   tkidx   = (int*)(w + 1024);
  float* tkw     = (float*)(w + 1024 + 65536);
  int*   ltok    = (int*)(w + 1024 + 2*65536);
  float* lwt     = (float*)(w + 1024 + 3*65536);
  short* xbf  = (short*)(w + 524288);
  short* hbuf = xbf + (size_t)TT * DD;                     // 2T x M bf16
  short* w0t  = hbuf + (size_t)2 * TT * MM;
  short* w1t  = w0t + (size_t)NE * DD * MM;
  short* wot  = w1t + (size_t)NE * DD * MM;

  hipMemsetAsync(counts, 0, 64, stream);
  hipMemsetAsync(out, 0, sizeof(float) * (size_t)out_size, stream);

  cvt_kernel<<<1024, 256, 0, stream>>>(x, xbf, (size_t)TT * DD);
  gate_kernel<<<TT, 256, 0, stream>>>(x, gk, counts, tkidx, tkw);
  scatter_kernel<<<1, 256, 0, stream>>>(counts, offsets, tkidx, tkw, ltok, lwt);
  tcvt_kernel<<<dim3(MM/64, DD/64, 24), 256, 0, stream>>>(wi0, wi1, wo, w0t, w1t, wot);

  gemm1_fast<<<dim3(MAXT1, MM/128), 512, 0, stream>>>(xbf, w0t, w1t, offsets, ltok, lwt, hbuf);
  gemm2_fast<<<dim3(MAXT2, DD/256), 512, 0, stream>>>(hbuf, wot, offsets, ltok, out);
}

// Round 6
// 1018.620 us; speedup vs baseline: 1.1753x; 1.1753x over previous
//
#include <hip/hip_runtime.h>
#include <hip/hip_bf16.h>
#include <stdint.h>

#define TT   8192   // B*S tokens
#define DD   2048
#define MM   2048
#define NE   8

typedef float f32x4 __attribute__((ext_vector_type(4)));
typedef short s16x8 __attribute__((ext_vector_type(8)));
typedef unsigned int u32;

static __device__ __forceinline__ short f2bf(float f) {
  __hip_bfloat16 h = __float2bfloat16(f);
  short s;
  __builtin_memcpy(&s, &h, 2);
  return s;
}

static __device__ __forceinline__ void gload_lds16(const short* g, short* lds) {
  __builtin_amdgcn_global_load_lds(
      (const __attribute__((address_space(1))) u32*)g,
      (__attribute__((address_space(3))) u32*)lds, 16, 0, 0);
}

#define VMCNT(n) asm volatile("s_waitcnt vmcnt(" #n ")" ::: "memory")
#define LGKM0()  asm volatile("s_waitcnt lgkmcnt(0)" ::: "memory")
#define BAR()    __builtin_amdgcn_s_barrier()
#define MFMA(a_, b_, c_) __builtin_amdgcn_mfma_f32_16x16x32_bf16(a_, b_, c_, 0, 0, 0)

// ---------------- fp32 -> bf16 conversion (x) ----------------
__global__ __launch_bounds__(256) void cvt_kernel(const float* __restrict__ in,
                                                  short* __restrict__ out, size_t n) {
  size_t idx = ((size_t)blockIdx.x * 256 + threadIdx.x) * 8;
  size_t stride = (size_t)gridDim.x * 256 * 8;
  for (size_t i = idx; i < n; i += stride) {
    f32x4 a = *(const f32x4*)(in + i);
    f32x4 b = *(const f32x4*)(in + i + 4);
    s16x8 v;
    v[0]=f2bf(a[0]); v[1]=f2bf(a[1]); v[2]=f2bf(a[2]); v[3]=f2bf(a[3]);
    v[4]=f2bf(b[0]); v[5]=f2bf(b[1]); v[6]=f2bf(b[2]); v[7]=f2bf(b[3]);
    *(s16x8*)(out + i) = v;
  }
}

// ---------------- fp32 -> bf16 transposing conversion (weights) ----------------
__global__ __launch_bounds__(256) void tcvt_kernel(
    const float* __restrict__ w0, const float* __restrict__ w1, const float* __restrict__ w2,
    short* __restrict__ o0, short* __restrict__ o1, short* __restrict__ o2) {
  __shared__ short tile[64][65];
  const int bz = blockIdx.z;
  const float* in; short* out;
  if (bz < 8)       { in = w0; out = o0; }
  else if (bz < 16) { in = w1; out = o1; }
  else              { in = w2; out = o2; }
  const int ex = bz & 7;
  const float* src = in + (size_t)ex * DD * MM;
  short* dst = out + (size_t)ex * DD * MM;
  const int r0 = blockIdx.y * 64;
  const int c0 = blockIdx.x * 64;
  const int t = threadIdx.x;
  const int rr = t >> 4, cc = (t & 15) * 4;
  #pragma unroll
  for (int i = 0; i < 4; i++) {
    int row = rr + i * 16;
    f32x4 v = *(const f32x4*)(src + (size_t)(r0 + row) * MM + c0 + cc);
    tile[cc + 0][row] = f2bf(v[0]);
    tile[cc + 1][row] = f2bf(v[1]);
    tile[cc + 2][row] = f2bf(v[2]);
    tile[cc + 3][row] = f2bf(v[3]);
  }
  __syncthreads();
  const int orow = t >> 2, c8 = (t & 3) * 16;
  s16x8 v0, v1;
  #pragma unroll
  for (int i = 0; i < 8; i++) { v0[i] = tile[orow][c8 + i]; v1[i] = tile[orow][c8 + 8 + i]; }
  short* dp = dst + (size_t)(c0 + orow) * DD + r0 + c8;
  *(s16x8*)(dp) = v0;
  *(s16x8*)(dp + 8) = v1;
}

// ---------------- gate: fp32 logits, top-2, softmax ----------------
__global__ __launch_bounds__(256) void gate_kernel(const float* __restrict__ x,
    const float* __restrict__ gk, int* __restrict__ counts,
    int* __restrict__ tkidx, float* __restrict__ tkw) {
  int t = blockIdx.x;
  const float* xr = x + (size_t)t * DD;
  float acc[NE];
  #pragma unroll
  for (int e = 0; e < NE; e++) acc[e] = 0.f;
  for (int d = threadIdx.x; d < DD; d += 256) {
    float xv = xr[d];
    const float* g = gk + (size_t)d * NE;
    #pragma unroll
    for (int e = 0; e < NE; e++) acc[e] += xv * g[e];
  }
  #pragma unroll
  for (int e = 0; e < NE; e++) {
    #pragma unroll
    for (int off = 32; off >= 1; off >>= 1)
      acc[e] += __shfl_xor(acc[e], off, 64);
  }
  __shared__ float red[4][NE];
  int wid = threadIdx.x >> 6;
  int lane = threadIdx.x & 63;
  if (lane == 0) {
    #pragma unroll
    for (int e = 0; e < NE; e++) red[wid][e] = acc[e];
  }
  __syncthreads();
  if (threadIdx.x == 0) {
    float l[NE];
    #pragma unroll
    for (int e = 0; e < NE; e++) l[e] = red[0][e] + red[1][e] + red[2][e] + red[3][e];
    int i1 = 0; float v1 = l[0];
    #pragma unroll
    for (int e = 1; e < NE; e++) if (l[e] > v1) { v1 = l[e]; i1 = e; }
    int i2 = -1; float v2 = -1e30f;
    #pragma unroll
    for (int e = 0; e < NE; e++) if (e != i1 && l[e] > v2) { v2 = l[e]; i2 = e; }
    float p = __expf(v2 - v1);
    float inv = 1.f / (1.f + p);
    tkidx[t*2]   = i1; tkidx[t*2+1] = i2;
    tkw[t*2]     = inv; tkw[t*2+1]  = p * inv;
    atomicAdd(&counts[i1], 1);
    atomicAdd(&counts[i2], 1);
  }
}

// ---------------- scatter into per-expert compact lists ----------------
__global__ __launch_bounds__(256) void scatter_kernel(const int* __restrict__ counts,
    int* __restrict__ offsets, const int* __restrict__ tkidx,
    const float* __restrict__ tkw, int* __restrict__ ltok, float* __restrict__ lwt) {
  __shared__ int soff[NE];
  __shared__ int scur[NE];
  if (threadIdx.x == 0) {
    int s = 0;
    for (int e = 0; e < NE; e++) { offsets[e] = s; soff[e] = s; s += counts[e]; scur[e] = 0; }
    offsets[NE] = s;
  }
  __syncthreads();
  for (int i = threadIdx.x; i < TT * 2; i += 256) {
    int e = tkidx[i];
    int pos = atomicAdd(&scur[e], 1);
    int dst = soff[e] + pos;
    ltok[dst] = i >> 1;
    lwt[dst]  = tkw[i];
  }
}

// ---------------- segment lookup ----------------
__device__ __forceinline__ void find_seg(const int* __restrict__ offsets, int tile, int bm,
                                         int& e, int& row0, int& rows, int& seg) {
  e = -1; row0 = 0; rows = 0; seg = 0;
  int accT = 0, prev = offsets[0];
  #pragma unroll
  for (int i = 0; i < NE; i++) {
    int nxt = offsets[i+1];
    int cnt = nxt - prev;
    int nt = (cnt + bm - 1) / bm;
    if (e < 0 && tile < accT + nt) { e = i; row0 = (tile - accT) * bm; rows = cnt; seg = prev; }
    accT += nt; prev = nxt;
  }
}

// ================= GEMM1: m201-style 4-phase pipeline =================
// BM=256 rows x 128 cols per weight matrix (dual B), BK=64. 512 thr = 8 waves (2Mx4N).
// Phase = {ds_read frags, 2x gload prefetch, BAR, lgkm0, 16 MFMA, counted VMCNT, BAR}.
// Per-wave staging units (2 loads each), issue order = use order [aL, B0, B1, aH].
#define MAXT_G 72

__global__ __launch_bounds__(512, 2) void gemm1_fast(
    const short* __restrict__ xbf,
    const short* __restrict__ w0t, const short* __restrict__ w1t,
    const int* __restrict__ offsets,
    const int* __restrict__ ltok, const float* __restrict__ lwt,
    short* __restrict__ hbuf) {
  __shared__ short As[2][256 * 64];
  __shared__ short B0s[2][128 * 64];
  __shared__ short B1s[2][128 * 64];
  __shared__ float w_s[256];

  const int tile = blockIdx.x;
  const int n0 = blockIdx.y * 128;
  int e, row0, rows, seg;
  find_seg(offsets, tile, 256, e, row0, rows, seg);
  if (e < 0) return;

  const int tid = threadIdx.x;
  const int lane = tid & 63, wid = tid >> 6;
  if (tid < 256) {
    int gr = row0 + tid;
    w_s[tid] = (gr < rows) ? lwt[seg + gr] : 0.f;
  }

  const int swz = ((lane & 7) ^ (lane >> 3)) * 8;   // pre-swizzled source offset (shorts)
  const int lrow = lane >> 3;                        // 0..7

  // A staging: aL set = rows {0-63,128-191}, aH = {64-127,192-255}; 16 rows per wave each.
  const int RL = (wid & 3) * 16 + (wid >> 2) * 128;
  const int RH = RL + 64;
  const short* aLp0; const short* aLp1; const short* aHp0; const short* aHp1;
  {
    int g0 = row0 + RL + lrow;      if (g0 >= rows) g0 = rows - 1;
    int g1 = row0 + RL + 8 + lrow;  if (g1 >= rows) g1 = rows - 1;
    int g2 = row0 + RH + lrow;      if (g2 >= rows) g2 = rows - 1;
    int g3 = row0 + RH + 8 + lrow;  if (g3 >= rows) g3 = rows - 1;
    aLp0 = xbf + (size_t)ltok[seg + g0] * DD + swz;
    aLp1 = xbf + (size_t)ltok[seg + g1] * DD + swz;
    aHp0 = xbf + (size_t)ltok[seg + g2] * DD + swz;
    aHp1 = xbf + (size_t)ltok[seg + g3] * DD + swz;
  }
  // B staging: wave wid stages rows wid*16..+15 of each B tile.
  const int RB = wid * 16;
  const short* b0p0 = w0t + ((size_t)e * MM + (n0 + RB + lrow)) * DD + swz;
  const short* b0p1 = w0t + ((size_t)e * MM + (n0 + RB + 8 + lrow)) * DD + swz;
  const short* b1p0 = w1t + ((size_t)e * MM + (n0 + RB + lrow)) * DD + swz;
  const short* b1p1 = w1t + ((size_t)e * MM + (n0 + RB + 8 + lrow)) * DD + swz;

  const int wr = wid >> 2, wn = wid & 3;
  const int lr = lane & 15;
  const int kq = (lane >> 4) * 8;
  const int lq = lane >> 4;

  f32x4 acc0[8][2], acc1[8][2];
  #pragma unroll
  for (int i = 0; i < 8; i++)
    #pragma unroll
    for (int j = 0; j < 2; j++) { acc0[i][j] = 0.f; acc1[i][j] = 0.f; }

  int brow_[2], bkey_[2];
  #pragma unroll
  for (int ni = 0; ni < 2; ni++) {
    brow_[ni] = wn * 32 + ni * 16 + lr;
    bkey_[ni] = (brow_[ni] & 7) * 8;
  }

  __syncthreads();   // w_s visible

  // prologue: tile 0 -> buf 0, order [aL, B0, B1, aH]
  gload_lds16(aLp0, &As[0][RL * 64]);
  gload_lds16(aLp1, &As[0][(RL + 8) * 64]);
  gload_lds16(b0p0, &B0s[0][RB * 64]);
  gload_lds16(b0p1, &B0s[0][(RB + 8) * 64]);
  gload_lds16(b1p0, &B1s[0][RB * 64]);
  gload_lds16(b1p1, &B1s[0][(RB + 8) * 64]);
  gload_lds16(aHp0, &As[0][RH * 64]);
  gload_lds16(aHp1, &As[0][(RH + 8) * 64]);
  VMCNT(4);          // aL0,B0_0 done
  __syncthreads();

  const int NT = DD / 64;
  int b = 0;
  for (int t = 0; t < NT; ++t, b ^= 1) {
    const int nb = b ^ 1;
    const bool pf = (t + 1 < NT);
    const int kn = (t + 1) * 64;
    short* Ab  = &As[b][0];
    short* B0b = &B0s[b][0];
    short* B1b = &B1s[b][0];
    s16x8 aks0[4], aks1[4], bks0[2], bks1[2], cks0[2], cks1[2];

    // ===== ph0: miL x mat0 =====
    #pragma unroll
    for (int mi = 0; mi < 4; mi++) {
      int ar = wr * 128 + mi * 16 + lr; int ak = (ar & 7) * 8;
      aks0[mi] = *(const s16x8*)&Ab[ar * 64 + (kq ^ ak)];
      aks1[mi] = *(const s16x8*)&Ab[ar * 64 + ((32 + kq) ^ ak)];
    }
    #pragma unroll
    for (int ni = 0; ni < 2; ni++) {
      bks0[ni] = *(const s16x8*)&B0b[brow_[ni] * 64 + (kq ^ bkey_[ni])];
      bks1[ni] = *(const s16x8*)&B0b[brow_[ni] * 64 + ((32 + kq) ^ bkey_[ni])];
    }
    if (pf) { gload_lds16(aLp0 + kn, &As[nb][RL * 64]); gload_lds16(aLp1 + kn, &As[nb][(RL + 8) * 64]); }
    BAR();
    LGKM0();
    __builtin_amdgcn_s_setprio(1);
    #pragma unroll
    for (int mi = 0; mi < 4; mi++)
      #pragma unroll
      for (int ni = 0; ni < 2; ni++) {
        acc0[mi][ni] = MFMA(aks0[mi], bks0[ni], acc0[mi][ni]);
        acc0[mi][ni] = MFMA(aks1[mi], bks1[ni], acc0[mi][ni]);
      }
    __builtin_amdgcn_s_setprio(0);
    if (pf) { VMCNT(4); } else { VMCNT(2); }
    BAR();

    // ===== ph1: miL x mat1 =====
    #pragma unroll
    for (int ni = 0; ni < 2; ni++) {
      cks0[ni] = *(const s16x8*)&B1b[brow_[ni] * 64 + (kq ^ bkey_[ni])];
      cks1[ni] = *(const s16x8*)&B1b[brow_[ni] * 64 + ((32 + kq) ^ bkey_[ni])];
    }
    if (pf) { gload_lds16(b0p0 + kn, &B0s[nb][RB * 64]); gload_lds16(b0p1 + kn, &B0s[nb][(RB + 8) * 64]); }
    BAR();
    LGKM0();
    __builtin_amdgcn_s_setprio(1);
    #pragma unroll
    for (int mi = 0; mi < 4; mi++)
      #pragma unroll
      for (int ni = 0; ni < 2; ni++) {
        acc1[mi][ni] = MFMA(aks0[mi], cks0[ni], acc1[mi][ni]);
        acc1[mi][ni] = MFMA(aks1[mi], cks1[ni], acc1[mi][ni]);
      }
    __builtin_amdgcn_s_setprio(0);
    if (pf) { VMCNT(4); } else { VMCNT(0); }
    BAR();

    // ===== ph2: miH x mat0 (b0 regs reused) =====
    #pragma unroll
    for (int mi = 0; mi < 4; mi++) {
      int ar = wr * 128 + (mi + 4) * 16 + lr; int ak = (ar & 7) * 8;
      aks0[mi] = *(const s16x8*)&Ab[ar * 64 + (kq ^ ak)];
      aks1[mi] = *(const s16x8*)&Ab[ar * 64 + ((32 + kq) ^ ak)];
    }
    if (pf) { gload_lds16(b1p0 + kn, &B1s[nb][RB * 64]); gload_lds16(b1p1 + kn, &B1s[nb][(RB + 8) * 64]); }
    BAR();
    LGKM0();
    __builtin_amdgcn_s_setprio(1);
    #pragma unroll
    for (int mi = 0; mi < 4; mi++)
      #pragma unroll
      for (int ni = 0; ni < 2; ni++) {
        acc0[mi + 4][ni] = MFMA(aks0[mi], bks0[ni], acc0[mi + 4][ni]);
        acc0[mi + 4][ni] = MFMA(aks1[mi], bks1[ni], acc0[mi + 4][ni]);
      }
    __builtin_amdgcn_s_setprio(0);
    BAR();                                  // no vmcnt (ph3 reads nothing new)

    // ===== ph3: miH x mat1 (aH + b1 regs reused) =====
    if (pf) { gload_lds16(aHp0 + kn, &As[nb][RH * 64]); gload_lds16(aHp1 + kn, &As[nb][(RH + 8) * 64]); }
    BAR();
    __builtin_amdgcn_s_setprio(1);
    #pragma unroll
    for (int mi = 0; mi < 4; mi++)
      #pragma unroll
      for (int ni = 0; ni < 2; ni++) {
        acc1[mi + 4][ni] = MFMA(aks0[mi], cks0[ni], acc1[mi + 4][ni]);
        acc1[mi + 4][ni] = MFMA(aks1[mi], cks1[ni], acc1[mi + 4][ni]);
      }
    __builtin_amdgcn_s_setprio(0);
    if (pf) { VMCNT(4); }
    BAR();
  }

  // ---- epilogue: silu(h0)*h1*w -> bf16 hbuf ----
  #pragma unroll
  for (int mi = 0; mi < 8; mi++) {
    #pragma unroll
    for (int jj = 0; jj < 4; jj++) {
      int r = wr * 128 + mi * 16 + lq * 4 + jj;
      int gr = row0 + r;
      if (gr < rows) {
        float wgt = w_s[r];
        size_t hrow = (size_t)(seg + gr) * MM + n0;
        #pragma unroll
        for (int ni = 0; ni < 2; ni++) {
          int c = wn * 32 + ni * 16 + lr;
          float g = acc0[mi][ni][jj];
          float u = acc1[mi][ni][jj];
          float act = g / (1.f + __expf(-g));
          hbuf[hrow + c] = f2bf(act * u * wgt);
        }
      }
    }
  }
}

// ================= GEMM2: m201-style 2-phase pipeline =================
// BM=256, BN=128, BK=64. 512 thr = 8 waves (2Mx4N), per wave 128x32.
// Units [aL, B, aH]; ph0: read aL+B frags, stage aL'+B'; ph1: read aH, stage aH'.
__global__ __launch_bounds__(512, 2) void gemm2_fast(
    const short* __restrict__ hbuf,
    const short* __restrict__ wot,
    const int* __restrict__ offsets,
    const int* __restrict__ ltok,
    float* __restrict__ out) {
  __shared__ short As[2][256 * 64];
  __shared__ short Bs[2][128 * 64];
  __shared__ int tok_s[256];

  const int tile = blockIdx.x;
  const int n0 = blockIdx.y * 128;
  int e, row0, rows, seg;
  find_seg(offsets, tile, 256, e, row0, rows, seg);
  if (e < 0) return;

  const int tid = threadIdx.x;
  const int lane = tid & 63, wid = tid >> 6;
  if (tid < 256) {
    int gr = row0 + tid;
    tok_s[tid] = (gr < rows) ? ltok[seg + gr] : -1;
  }

  const int swz = ((lane & 7) ^ (lane >> 3)) * 8;
  const int lrow = lane >> 3;

  const int RL = (wid & 3) * 16 + (wid >> 2) * 128;
  const int RH = RL + 64;
  const short* aLp0; const short* aLp1; const short* aHp0; const short* aHp1;
  {
    int g0 = row0 + RL + lrow;      if (g0 >= rows) g0 = rows - 1;
    int g1 = row0 + RL + 8 + lrow;  if (g1 >= rows) g1 = rows - 1;
    int g2 = row0 + RH + lrow;      if (g2 >= rows) g2 = rows - 1;
    int g3 = row0 + RH + 8 + lrow;  if (g3 >= rows) g3 = rows - 1;
    aLp0 = hbuf + (size_t)(seg + g0) * MM + swz;
    aLp1 = hbuf + (size_t)(seg + g1) * MM + swz;
    aHp0 = hbuf + (size_t)(seg + g2) * MM + swz;
    aHp1 = hbuf + (size_t)(seg + g3) * MM + swz;
  }
  const int RB = wid * 16;
  const short* bp0 = wot + ((size_t)e * DD + (n0 + RB + lrow)) * MM + swz;
  const short* bp1 = wot + ((size_t)e * DD + (n0 + RB + 8 + lrow)) * MM + swz;

  const int wr = wid >> 2, wn = wid & 3;
  const int lr = lane & 15;
  const int kq = (lane >> 4) * 8;
  const int lq = lane >> 4;

  f32x4 acc[8][2];
  #pragma unroll
  for (int i = 0; i < 8; i++)
    #pragma unroll
    for (int j = 0; j < 2; j++) acc[i][j] = 0.f;

  int brow_[2], bkey_[2];
  #pragma unroll
  for (int ni = 0; ni < 2; ni++) {
    brow_[ni] = wn * 32 + ni * 16 + lr;
    bkey_[ni] = (brow_[ni] & 7) * 8;
  }

  __syncthreads();

  // prologue: [aL, B, aH] -> buf 0
  gload_lds16(aLp0, &As[0][RL * 64]);
  gload_lds16(aLp1, &As[0][(RL + 8) * 64]);
  gload_lds16(bp0, &Bs[0][RB * 64]);
  gload_lds16(bp1, &Bs[0][(RB + 8) * 64]);
  gload_lds16(aHp0, &As[0][RH * 64]);
  gload_lds16(aHp1, &As[0][(RH + 8) * 64]);
  VMCNT(2);          // aL0,B0 done
  __syncthreads();

  const int NT = MM / 64;
  int b = 0;
  for (int t = 0; t < NT; ++t, b ^= 1) {
    const int nb = b ^ 1;
    const bool pf = (t + 1 < NT);
    const int kn = (t + 1) * 64;
    short* Ab = &As[b][0];
    short* Bb = &Bs[b][0];
    s16x8 aks0[4], aks1[4], bks0[2], bks1[2];

    // ===== ph0: miL =====
    #pragma unroll
    for (int mi = 0; mi < 4; mi++) {
      int ar = wr * 128 + mi * 16 + lr; int ak = (ar & 7) * 8;
      aks0[mi] = *(const s16x8*)&Ab[ar * 64 + (kq ^ ak)];
      aks1[mi] = *(const s16x8*)&Ab[ar * 64 + ((32 + kq) ^ ak)];
    }
    #pragma unroll
    for (int ni = 0; ni < 2; ni++) {
      bks0[ni] = *(const s16x8*)&Bb[brow_[ni] * 64 + (kq ^ bkey_[ni])];
      bks1[ni] = *(const s16x8*)&Bb[brow_[ni] * 64 + ((32 + kq) ^ bkey_[ni])];
    }
    if (pf) {
      gload_lds16(aLp0 + kn, &As[nb][RL * 64]); gload_lds16(aLp1 + kn, &As[nb][(RL + 8) * 64]);
      gload_lds16(bp0 + kn, &Bs[nb][RB * 64]);  gload_lds16(bp1 + kn, &Bs[nb][(RB + 8) * 64]);
    }
    BAR();
    LGKM0();
    __builtin_amdgcn_s_setprio(1);
    #pragma unroll
    for (int mi = 0; mi < 4; mi++)
      #pragma unroll
      for (int ni = 0; ni < 2; ni++) {
        acc[mi][ni] = MFMA(aks0[mi], bks0[ni], acc[mi][ni]);
        acc[mi][ni] = MFMA(aks1[mi], bks1[ni], acc[mi][ni]);
      }
    __builtin_amdgcn_s_setprio(0);
    if (pf) { VMCNT(4); } else { VMCNT(0); }
    BAR();

    // ===== ph1: miH (b regs reused) =====
    #pragma unroll
    for (int mi = 0; mi < 4; mi++) {
      int ar = wr * 128 + (mi + 4) * 16 + lr; int ak = (ar & 7) * 8;
      aks0[mi] = *(const s16x8*)&Ab[ar * 64 + (kq ^ ak)];
      aks1[mi] = *(const s16x8*)&Ab[ar * 64 + ((32 + kq) ^ ak)];
    }
    if (pf) { gload_lds16(aHp0 + kn, &As[nb][RH * 64]); gload_lds16(aHp1 + kn, &As[nb][(RH + 8) * 64]); }
    BAR();
    LGKM0();
    __builtin_amdgcn_s_setprio(1);
    #pragma unroll
    for (int mi = 0; mi < 4; mi++)
      #pragma unroll
      for (int ni = 0; ni < 2; ni++) {
        acc[mi + 4][ni] = MFMA(aks0[mi], bks0[ni], acc[mi + 4][ni]);
        acc[mi + 4][ni] = MFMA(aks1[mi], bks1[ni], acc[mi + 4][ni]);
      }
    __builtin_amdgcn_s_setprio(0);
    if (pf) { VMCNT(2); }
    BAR();
  }

  #pragma unroll
  for (int mi = 0; mi < 8; mi++) {
    #pragma unroll
    for (int jj = 0; jj < 4; jj++) {
      int r = wr * 128 + mi * 16 + lq * 4 + jj;
      int gr = row0 + r;
      if (gr < rows) {
        size_t orow = (size_t)tok_s[r] * DD + n0;
        #pragma unroll
        for (int ni = 0; ni < 2; ni++) {
          int c = wn * 32 + ni * 16 + lr;
          atomicAdd(&out[orow + c], acc[mi][ni][jj]);
        }
      }
    }
  }
}

// ---------------- launcher ----------------
extern "C" void kernel_launch(void* const* d_in, const int* in_sizes, int n_in,
                              void* d_out, int out_size, void* d_ws, size_t ws_size,
                              hipStream_t stream) {
  const float* x   = (const float*)d_in[0];
  const float* gk  = (const float*)d_in[1];
  const float* wi0 = (const float*)d_in[2];
  const float* wi1 = (const float*)d_in[3];
  const float* wo  = (const float*)d_in[4];
  float* out = (float*)d_out;

  char* w = (char*)d_ws;
  int*   counts  = (int*)(w);
  int*   offsets = (int*)(w + 256);
  int*   tkidx   = (int*)(w + 1024);
  float* tkw     = (float*)(w + 1024 + 65536);
  int*   ltok    = (int*)(w + 1024 + 2*65536);
  float* lwt     = (float*)(w + 1024 + 3*65536);
  short* xbf  = (short*)(w + 524288);
  short* hbuf = xbf + (size_t)TT * DD;                     // 2T x M bf16
  short* w0t  = hbuf + (size_t)2 * TT * MM;
  short* w1t  = w0t + (size_t)NE * DD * MM;
  short* wot  = w1t + (size_t)NE * DD * MM;

  hipMemsetAsync(counts, 0, 64, stream);
  hipMemsetAsync(out, 0, sizeof(float) * (size_t)out_size, stream);

  cvt_kernel<<<1024, 256, 0, stream>>>(x, xbf, (size_t)TT * DD);
  gate_kernel<<<TT, 256, 0, stream>>>(x, gk, counts, tkidx, tkw);
  scatter_kernel<<<1, 256, 0, stream>>>(counts, offsets, tkidx, tkw, ltok, lwt);
  tcvt_kernel<<<dim3(MM/64, DD/64, 24), 256, 0, stream>>>(wi0, wi1, wo, w0t, w1t, wot);

  gemm1_fast<<<dim3(MAXT_G, MM/128), 512, 0, stream>>>(xbf, w0t, w1t, offsets, ltok, lwt, hbuf);
  gemm2_fast<<<dim3(MAXT_G, DD/128), 512, 0, stream>>>(hbuf, wot, offsets, ltok, out);
}